// Round 1
// baseline (10547.565 us; speedup 1.0000x reference)
//
#include <hip/hip_runtime.h>

// Bidirectional "LSTM" (degenerate per reference): fwd = single cell on last
// timestep; bwd = 128-step h-only recurrence (c stays 0 -> f-gate dead).
// Strategy: bf16 hi/lo split 3-pass MFMA (fp32-accurate), i/g/o gates only.

#define B_    256
#define S_    128
#define E_    1024
#define H_    2048
#define VOC_  50000

typedef __bf16 bf16;
typedef bf16  bf16x8 __attribute__((ext_vector_type(8)));
typedef float f32x4  __attribute__((ext_vector_type(4)));
typedef float f32x16 __attribute__((ext_vector_type(16)));

typedef const char __attribute__((address_space(1)))* gas1_t;
typedef char       __attribute__((address_space(3)))* las3_t;

// ---------------------------------------------------------------------------
// Weight pack: W[8192,K] f32 -> per (jstrip,chunk) 24KB blocks laid out in the
// exact LDS image the GEMM consumes: [hl][gate][kk][lane][16B].
// gate g in {0,1,2} -> original rows {j, 4096+j, 6144+j} (i, g, o).
// Fragment: lane l holds j=l&31, k = kk*16 + (l>>5)*8 + e  (32x32x16 B-frag).
// ---------------------------------------------------------------------------
__global__ __launch_bounds__(256) void pack_w(const float* __restrict__ W,
                                              char* __restrict__ dst, int nchunks) {
  int p = blockIdx.x * 256 + threadIdx.x;
  int lane = p & 63; p >>= 6;
  int kk   = p & 3;  p >>= 2;
  int g    = p % 3;  p /= 3;
  int hl   = p & 1;  p >>= 1;
  int c    = p % nchunks;
  int jstrip = p / nchunks;
  int K  = nchunks * 64;
  int j  = jstrip * 32 + (lane & 31);
  int k0 = c * 64 + kk * 16 + (lane >> 5) * 8;
  int grow = j + (g == 1 ? 4096 : (g == 2 ? 6144 : 0));
  const float* src = W + (size_t)grow * K + k0;
  f32x4 v0 = *(const f32x4*)src;
  f32x4 v1 = *(const f32x4*)(src + 4);
  float f[8] = {v0[0], v0[1], v0[2], v0[3], v1[0], v1[1], v1[2], v1[3]};
  bf16x8 o;
#pragma unroll
  for (int e = 0; e < 8; ++e) {
    float x = f[e];
    bf16 hb = (bf16)x;
    o[e] = hl ? (bf16)(x - (float)hb) : hb;
  }
  size_t off = (size_t)(jstrip * nchunks + c) * 24576
             + (size_t)((hl * 3 + g) * 4 + kk) * 1024 + lane * 16;
  *(bf16x8*)(dst + off) = o;
}

__global__ __launch_bounds__(256) void pack_bias(const float* __restrict__ bib,
                                                 const float* __restrict__ bhb,
                                                 const float* __restrict__ bif,
                                                 const float* __restrict__ bhf,
                                                 float* __restrict__ B3B,
                                                 float* __restrict__ B3F) {
  int t = blockIdx.x * 256 + threadIdx.x;       // 2*3*2048 = 12288
  int which = t / 6144;
  int r = t % 6144;
  int g = r >> 11, j = r & 2047;
  int grow = j + (g == 1 ? 4096 : (g == 2 ? 6144 : 0));
  if (which == 0) B3B[g * 2048 + j] = bib[grow] + bhb[grow];
  else            B3F[g * 2048 + j] = bif[grow] + bhf[grow];
}

// ---------------------------------------------------------------------------
// Embedding gather into time-REVERSED, MFMA-A-fragment-swizzled hi/lo bf16.
// A layout: addr(b,k) = ((k>>4)*8 + (b>>5))*1024 + ((b&31) + 32*((k>>3)&1))*16
//           + (k&7)*2    -> wave frag load = one contiguous 1KB dwordx4.
// Xr[t] = embeds[:, S-1-t]; Xr[0] also serves the forward cell.
// ---------------------------------------------------------------------------
__global__ __launch_bounds__(256) void gather_k(const int* __restrict__ inputs,
                                                const float* __restrict__ emb,
                                                char* __restrict__ XH,
                                                char* __restrict__ XL) {
  int p = blockIdx.x * 256 + threadIdx.x;       // 128*8*64*64 = 4,194,304
  int l   = p & 63; p >>= 6;
  int k16 = p & 63; p >>= 6;
  int b32 = p & 7;  p >>= 3;
  int t   = p;                                   // 0..127
  int b  = b32 * 32 + (l & 31);
  int e0 = k16 * 16 + (l >> 5) * 8;
  int s  = (S_ - 1) - t;
  int iv = inputs[b * S_ + s];
  if ((unsigned)iv >= (unsigned)VOC_) iv = 0;    // reference's where(>VOCAB,0) + OOB guard
  const float* src = emb + (size_t)iv * E_ + e0;
  f32x4 v0 = *(const f32x4*)src;
  f32x4 v1 = *(const f32x4*)(src + 4);
  float f[8] = {v0[0], v0[1], v0[2], v0[3], v1[0], v1[1], v1[2], v1[3]};
  bf16x8 vh, vl;
#pragma unroll
  for (int e = 0; e < 8; ++e) {
    bf16 hb = (bf16)f[e];
    vh[e] = hb;
    vl[e] = (bf16)(f[e] - (float)hb);
  }
  size_t off = (size_t)t * 524288 + (size_t)(k16 * 8 + b32) * 1024 + l * 16;
  *(bf16x8*)(XH + off) = vh;
  *(bf16x8*)(XL + off) = vl;
}

// ---------------------------------------------------------------------------
// Split-K GEMM: grid (64 jstrips, nslices). WG = 2 waves, BM=256 (wave: 128m x
// 32j x 3gates, mfma_f32_32x32x16_bf16, 3-pass hi/lo). Virtual chunk list:
// nHc h-chunks (K=64 each) then nXc x-chunks. Weights staged to LDS via
// global_load_lds (dbuf); A loaded direct-to-reg (1KB coalesced frags).
// Writes f32 partials [slice][b][gate][2048].
// ---------------------------------------------------------------------------
__global__ __launch_bounds__(128, 1) void gemm_k(
    const char* __restrict__ AhH, const char* __restrict__ AhL, int nHc,
    const char* __restrict__ AxH, const char* __restrict__ AxL,
    const char* __restrict__ Wh,  const char* __restrict__ Wx,  int nXc,
    float* __restrict__ partial, int cps) {
  __shared__ __attribute__((aligned(16))) char Bsm[2][24576];
  const int jstrip = blockIdx.x, slice = blockIdx.y;
  const int tid = threadIdx.x;
  const int wid = tid >> 6, lane = tid & 63;
  const int c0 = slice * cps;

  f32x16 acc[4][3] = {};

  auto stage = [&](int c, int buf) {
    const char* src = (c < nHc) ? (Wh + (size_t)(jstrip * nHc + c) * 24576)
                                : (Wx + (size_t)(jstrip * nXc + (c - nHc)) * 24576);
#pragma unroll
    for (int i = 0; i < 12; ++i) {
      int off = i * 2048 + wid * 1024;           // wave-uniform LDS base
      __builtin_amdgcn_global_load_lds((gas1_t)(src + off + lane * 16),
                                       (las3_t)(&Bsm[buf][off]), 16, 0, 0);
    }
  };

  auto compute = [&](int c, int buf) {
    const char* aH;
    const char* aL;
    int kb;
    if (c < nHc) { aH = AhH; aL = AhL; kb = c * 4; }
    else         { aH = AxH; aL = AxL; kb = (c - nHc) * 4; }
#pragma unroll
    for (int kk = 0; kk < 4; ++kk) {
      bf16x8 BH[3], BL[3];
#pragma unroll
      for (int g = 0; g < 3; ++g) {
        BH[g] = *(const bf16x8*)(&Bsm[buf][(g * 4 + kk) * 1024 + lane * 16]);
        BL[g] = *(const bf16x8*)(&Bsm[buf][((g + 3) * 4 + kk) * 1024 + lane * 16]);
      }
      const size_t krow = (size_t)(kb + kk) * 8192;   // k16 * (8 blocks * 1024B)
#pragma unroll
      for (int mf = 0; mf < 4; ++mf) {
        const size_t aoff = krow + (size_t)(wid * 4 + mf) * 1024 + lane * 16;
        bf16x8 AH = *(const bf16x8*)(aH + aoff);
        bf16x8 AL = *(const bf16x8*)(aL + aoff);
#pragma unroll
        for (int g = 0; g < 3; ++g) {
          acc[mf][g] = __builtin_amdgcn_mfma_f32_32x32x16_bf16(AH, BH[g], acc[mf][g], 0, 0, 0);
          acc[mf][g] = __builtin_amdgcn_mfma_f32_32x32x16_bf16(AL, BH[g], acc[mf][g], 0, 0, 0);
          acc[mf][g] = __builtin_amdgcn_mfma_f32_32x32x16_bf16(AH, BL[g], acc[mf][g], 0, 0, 0);
        }
      }
    }
  };

  stage(c0, 0);
  __syncthreads();
  for (int ci = 0; ci < cps; ++ci) {
    if (ci + 1 < cps) stage(c0 + ci + 1, (ci + 1) & 1);
    compute(c0 + ci, ci & 1);
    __syncthreads();
  }

  // epilogue: C/D 32x32 layout: col=lane&31, row=(r&3)+8*(r>>2)+4*(lane>>5)
  float* pb = partial + (size_t)slice * (B_ * 3 * 2048);
  const int jb = jstrip * 32 + (lane & 31);
  const int rb = wid * 128 + ((lane >> 5) << 2);
#pragma unroll
  for (int mf = 0; mf < 4; ++mf)
#pragma unroll
    for (int g = 0; g < 3; ++g)
#pragma unroll
      for (int r = 0; r < 16; ++r) {
        int b = rb + mf * 32 + (r & 3) + ((r >> 2) << 3);
        pb[((size_t)b * 3 + g) * 2048 + jb] = acc[mf][g][r];
      }
}

// ---------------------------------------------------------------------------
// Activation + slice reduction. h = sig(o)*tanh(sig(i)*tanh(g)) (c==0 always).
// Writes next-h as bf16 hi/lo in A-fragment layout, optional f32 to d_out.
// ---------------------------------------------------------------------------
__device__ __forceinline__ float sig_(float x) {
  x = fminf(fmaxf(x, -30.f), 30.f);
  return 1.f / (1.f + __expf(-x));
}
__device__ __forceinline__ float tanh_(float x) {
  x = fminf(fmaxf(x, -15.f), 15.f);
  float e = __expf(2.f * x);
  return (e - 1.f) / (e + 1.f);
}

__global__ __launch_bounds__(256) void act_k(const float* __restrict__ partial, int nsl,
                                             const float* __restrict__ bias3,
                                             char* __restrict__ hH, char* __restrict__ hL,
                                             float* __restrict__ out, int outcol) {
  const int b = blockIdx.x, t = threadIdx.x, j0 = t * 8;
  float gi[8], gg[8], go[8];
  {
    f32x4 a0 = *(const f32x4*)&bias3[j0],        a1 = *(const f32x4*)&bias3[j0 + 4];
    f32x4 b0 = *(const f32x4*)&bias3[2048 + j0], b1 = *(const f32x4*)&bias3[2048 + j0 + 4];
    f32x4 c0 = *(const f32x4*)&bias3[4096 + j0], c1 = *(const f32x4*)&bias3[4096 + j0 + 4];
#pragma unroll
    for (int e = 0; e < 4; ++e) {
      gi[e] = a0[e]; gi[e + 4] = a1[e];
      gg[e] = b0[e]; gg[e + 4] = b1[e];
      go[e] = c0[e]; go[e + 4] = c1[e];
    }
  }
  for (int s = 0; s < nsl; ++s) {
    const float* p = partial + (size_t)(s * B_ + b) * 6144;
    f32x4 a0 = *(const f32x4*)&p[j0],        a1 = *(const f32x4*)&p[j0 + 4];
    f32x4 b0 = *(const f32x4*)&p[2048 + j0], b1 = *(const f32x4*)&p[2048 + j0 + 4];
    f32x4 c0 = *(const f32x4*)&p[4096 + j0], c1 = *(const f32x4*)&p[4096 + j0 + 4];
#pragma unroll
    for (int e = 0; e < 4; ++e) {
      gi[e] += a0[e]; gi[e + 4] += a1[e];
      gg[e] += b0[e]; gg[e + 4] += b1[e];
      go[e] += c0[e]; go[e + 4] += c1[e];
    }
  }
  float h[8];
#pragma unroll
  for (int e = 0; e < 8; ++e)
    h[e] = sig_(go[e]) * tanh_(sig_(gi[e]) * tanh_(gg[e]));

  if (hH) {
    bf16x8 vh, vl;
#pragma unroll
    for (int e = 0; e < 8; ++e) {
      bf16 hb = (bf16)h[e];
      vh[e] = hb;
      vl[e] = (bf16)(h[e] - (float)hb);
    }
    size_t off = (size_t)((j0 >> 4) * 8 + (b >> 5)) * 1024
               + (size_t)((b & 31) + ((j0 >> 3) & 1) * 32) * 16;
    *(bf16x8*)(hH + off) = vh;
    *(bf16x8*)(hL + off) = vl;
  }
  if (out) {
    float* o = out + (size_t)b * 4096 + outcol + j0;
    f32x4 o0 = {h[0], h[1], h[2], h[3]}, o1 = {h[4], h[5], h[6], h[7]};
    *(f32x4*)o = o0;
    *(f32x4*)(o + 4) = o1;
  }
}

// ---------------------------------------------------------------------------
extern "C" void kernel_launch(void* const* d_in, const int* in_sizes, int n_in,
                              void* d_out, int out_size, void* d_ws, size_t ws_size,
                              hipStream_t stream) {
  const int*   inputs = (const int*)d_in[0];
  const float* embed  = (const float*)d_in[1];
  const float* Wihf   = (const float*)d_in[2];
  // d_in[3] = W_hh_f: unused (multiplied by zero state in reference)
  const float* bihf   = (const float*)d_in[4];
  const float* bhhf   = (const float*)d_in[5];
  const float* Wihb   = (const float*)d_in[6];
  const float* Whhb   = (const float*)d_in[7];
  const float* bihb   = (const float*)d_in[8];
  const float* bhhb   = (const float*)d_in[9];
  float* out = (float*)d_out;
  char*  ws  = (char*)d_ws;

  size_t o = 0;
  char* WHHp  = ws + o; o += 50331648;            // 64*32*24KB
  char* WIHBp = ws + o; o += 25165824;            // 64*16*24KB
  char* WIHFp = ws + o; o += 25165824;
  char* XRH   = ws + o; o += 67108864;            // 128 * 512KB
  char* XRL   = ws + o; o += 67108864;
  char* HB    = ws + o; o += 4 * 1048576;         // hi0, lo0, hi1, lo1
  float* B3B  = (float*)(ws + o); o += 24576;
  float* B3F  = (float*)(ws + o); o += 24576;
  float* PART = (float*)(ws + o); o += 50331648;  // 8 slices * 256*3*2048 f32
  // total ~276 MB; assumes ws_size covers it.

  hipMemsetAsync(HB, 0, 4 * 1048576, stream);     // h0 = zeros (hi & lo)

  pack_w<<<12288, 256, 0, stream>>>(Whhb, WHHp, 32);
  pack_w<<<6144, 256, 0, stream>>>(Wihb, WIHBp, 16);
  pack_w<<<6144, 256, 0, stream>>>(Wihf, WIHFp, 16);
  pack_bias<<<48, 256, 0, stream>>>(bihb, bhhb, bihf, bhhf, B3B, B3F);
  gather_k<<<16384, 256, 0, stream>>>(inputs, embed, XRH, XRL);

  // forward cell: x = Xr[0] (= embeds[:,-1]), h=c=0  -> d_out[:, 0:2048]
  gemm_k<<<dim3(64, 2), 128, 0, stream>>>(nullptr, nullptr, 0, XRH, XRL,
                                          nullptr, WIHFp, 16, PART, 8);
  act_k<<<256, 256, 0, stream>>>(PART, 2, B3F, nullptr, nullptr, out, 0);

  char* hHi[2] = {HB, HB + 2097152};
  char* hLo[2] = {HB + 1048576, HB + 3145728};

  for (int t = 0; t < S_; ++t) {
    gemm_k<<<dim3(64, 8), 128, 0, stream>>>(hHi[t & 1], hLo[t & 1], 32,
                                            XRH + (size_t)t * 524288,
                                            XRL + (size_t)t * 524288,
                                            WHHp, WIHBp, 16, PART, 6);
    act_k<<<256, 256, 0, stream>>>(PART, 8, B3B, hHi[(t & 1) ^ 1], hLo[(t & 1) ^ 1],
                                   (t == S_ - 1) ? out : nullptr, 2048);
  }
}

// Round 2
// 7060.751 us; speedup vs baseline: 1.4938x; 1.4938x over previous
//
#include <hip/hip_runtime.h>

// Bidirectional "LSTM" (degenerate per reference): fwd = single cell on last
// timestep; bwd = 128-step h-only recurrence (c stays 0 -> f-gate dead).
// R2: per-step kernel fuses rec(t) [K=2048] with pipelined xpart(t+2) [K=1024];
// uniform 768-WG grid (3/CU), 8-wave WGs; separate 512-WG act/reduce kernel.
// Numerics identical to R1 (3-pass bf16 hi/lo, f32 partials).

#define B_    256
#define S_    128
#define E_    1024
#define H_    2048
#define VOC_  50000

typedef __bf16 bf16;
typedef bf16  bf16x8 __attribute__((ext_vector_type(8)));
typedef float f32x4  __attribute__((ext_vector_type(4)));
typedef float f32x16 __attribute__((ext_vector_type(16)));

typedef const char __attribute__((address_space(1)))* gas1_t;
typedef char       __attribute__((address_space(3)))* las3_t;

// ---------------------------------------------------------------------------
// Weight pack: W[8192,K] f32 -> per (jstrip,chunk) 24KB blocks laid out in the
// exact LDS image the GEMM consumes: [hl][gate][kk][lane][16B].
// gate g in {0,1,2} -> original rows {j, 4096+j, 6144+j} (i, g, o).
// Fragment: lane l holds j=l&31, k = kk*16 + (l>>5)*8 + e  (32x32x16 B-frag).
// ---------------------------------------------------------------------------
__global__ __launch_bounds__(256) void pack_w(const float* __restrict__ W,
                                              char* __restrict__ dst, int nchunks) {
  int p = blockIdx.x * 256 + threadIdx.x;
  int lane = p & 63; p >>= 6;
  int kk   = p & 3;  p >>= 2;
  int g    = p % 3;  p /= 3;
  int hl   = p & 1;  p >>= 1;
  int c    = p % nchunks;
  int jstrip = p / nchunks;
  int K  = nchunks * 64;
  int j  = jstrip * 32 + (lane & 31);
  int k0 = c * 64 + kk * 16 + (lane >> 5) * 8;
  int grow = j + (g == 1 ? 4096 : (g == 2 ? 6144 : 0));
  const float* src = W + (size_t)grow * K + k0;
  f32x4 v0 = *(const f32x4*)src;
  f32x4 v1 = *(const f32x4*)(src + 4);
  float f[8] = {v0[0], v0[1], v0[2], v0[3], v1[0], v1[1], v1[2], v1[3]};
  bf16x8 o;
#pragma unroll
  for (int e = 0; e < 8; ++e) {
    float x = f[e];
    bf16 hb = (bf16)x;
    o[e] = hl ? (bf16)(x - (float)hb) : hb;
  }
  size_t off = (size_t)(jstrip * nchunks + c) * 24576
             + (size_t)((hl * 3 + g) * 4 + kk) * 1024 + lane * 16;
  *(bf16x8*)(dst + off) = o;
}

__global__ __launch_bounds__(256) void pack_bias(const float* __restrict__ bib,
                                                 const float* __restrict__ bhb,
                                                 const float* __restrict__ bif,
                                                 const float* __restrict__ bhf,
                                                 float* __restrict__ B3B,
                                                 float* __restrict__ B3F) {
  int t = blockIdx.x * 256 + threadIdx.x;       // 2*3*2048 = 12288
  int which = t / 6144;
  int r = t % 6144;
  int g = r >> 11, j = r & 2047;
  int grow = j + (g == 1 ? 4096 : (g == 2 ? 6144 : 0));
  if (which == 0) B3B[g * 2048 + j] = bib[grow] + bhb[grow];
  else            B3F[g * 2048 + j] = bif[grow] + bhf[grow];
}

// ---------------------------------------------------------------------------
// Embedding gather into time-REVERSED, MFMA-A-fragment-swizzled hi/lo bf16.
// A layout: addr(b,k) = ((k>>4)*8 + (b>>5))*1024 + ((b&31) + 32*((k>>3)&1))*16
//           + (k&7)*2   -> wave frag load = one contiguous 1KB dwordx4.
// Xr[t] = embeds[:, S-1-t]; Xr[0] also serves the forward cell.
// ---------------------------------------------------------------------------
__global__ __launch_bounds__(256) void gather_k(const int* __restrict__ inputs,
                                                const float* __restrict__ emb,
                                                char* __restrict__ XH,
                                                char* __restrict__ XL) {
  int p = blockIdx.x * 256 + threadIdx.x;       // 128*8*64*64 = 4,194,304
  int l   = p & 63; p >>= 6;
  int k16 = p & 63; p >>= 6;
  int b32 = p & 7;  p >>= 3;
  int t   = p;                                   // 0..127
  int b  = b32 * 32 + (l & 31);
  int e0 = k16 * 16 + (l >> 5) * 8;
  int s  = (S_ - 1) - t;
  int iv = inputs[b * S_ + s];
  if ((unsigned)iv >= (unsigned)VOC_) iv = 0;
  const float* src = emb + (size_t)iv * E_ + e0;
  f32x4 v0 = *(const f32x4*)src;
  f32x4 v1 = *(const f32x4*)(src + 4);
  float f[8] = {v0[0], v0[1], v0[2], v0[3], v1[0], v1[1], v1[2], v1[3]};
  bf16x8 vh, vl;
#pragma unroll
  for (int e = 0; e < 8; ++e) {
    bf16 hb = (bf16)f[e];
    vh[e] = hb;
    vl[e] = (bf16)(f[e] - (float)hb);
  }
  size_t off = (size_t)t * 524288 + (size_t)(k16 * 8 + b32) * 1024 + l * 16;
  *(bf16x8*)(XH + off) = vh;
  *(bf16x8*)(XL + off) = vl;
}

// ---------------------------------------------------------------------------
// One slice-WG of GEMM: 8 waves (512 thr), tile 256m x 96n(3 gates x 32j) x
// 256k (4 chunks of 64). Wave = 32m x 96n, acc 3 x f32x16. B staged to LDS
// (dbuf 2x24KB) via global_load_lds; A read direct-to-reg as 16B frags.
// Writes f32 partials to dst[b*96 + g*32 + j].
// ---------------------------------------------------------------------------
__device__ __forceinline__ void gemm4(const char* __restrict__ aH,
                                      const char* __restrict__ aL,
                                      const char* __restrict__ wp,
                                      int kb16,
                                      float* __restrict__ dst,
                                      char* sm) {
  const int tid = threadIdx.x;
  const int wid = tid >> 6, lane = tid & 63;
  f32x16 acc[3] = {};

  auto stage = [&](int c, int buf) {
    const char* src = wp + (size_t)c * 24576;
#pragma unroll
    for (int i = 0; i < 3; ++i) {
      int off = (i * 8 + wid) * 1024;            // wave-uniform LDS base
      __builtin_amdgcn_global_load_lds((gas1_t)(src + off + lane * 16),
                                       (las3_t)(sm + buf * 24576 + off), 16, 0, 0);
    }
  };

  stage(0, 0);
  __syncthreads();
#pragma unroll
  for (int c = 0; c < 4; ++c) {
    if (c < 3) stage(c + 1, (c + 1) & 1);
    const char* bs = sm + (c & 1) * 24576;
#pragma unroll
    for (int kk = 0; kk < 4; ++kk) {
      const size_t aoff = (size_t)((kb16 + c * 4 + kk) * 8 + wid) * 1024 + lane * 16;
      bf16x8 AH = *(const bf16x8*)(aH + aoff);
      bf16x8 AL = *(const bf16x8*)(aL + aoff);
#pragma unroll
      for (int g = 0; g < 3; ++g) {
        bf16x8 BH = *(const bf16x8*)(bs + (size_t)(g * 4 + kk) * 1024 + lane * 16);
        bf16x8 BL = *(const bf16x8*)(bs + (size_t)((g + 3) * 4 + kk) * 1024 + lane * 16);
        acc[g] = __builtin_amdgcn_mfma_f32_32x32x16_bf16(AH, BH, acc[g], 0, 0, 0);
        acc[g] = __builtin_amdgcn_mfma_f32_32x32x16_bf16(AL, BH, acc[g], 0, 0, 0);
        acc[g] = __builtin_amdgcn_mfma_f32_32x32x16_bf16(AH, BL, acc[g], 0, 0, 0);
      }
    }
    __syncthreads();
  }
  // C layout (32x32): col = lane&31, row = (r&3)+8*(r>>2)+4*(lane>>5)
#pragma unroll
  for (int g = 0; g < 3; ++g)
#pragma unroll
    for (int r = 0; r < 16; ++r) {
      int row = (r & 3) + ((r >> 2) << 3) + ((lane >> 5) << 2);
      int b = wid * 32 + row;
      dst[(size_t)b * 96 + g * 32 + (lane & 31)] = acc[g][r];
    }
}

// Per-step kernel: blocks 0..511 = rec(t) (8 kslices x 64 nstrips, K=2048),
// blocks 512..767 = xpart(t+2) (4 kslices x 64 nstrips, K=1024).
__global__ __launch_bounds__(512, 4) void step_gemm(
    const char* __restrict__ hH, const char* __restrict__ hL,
    const char* __restrict__ xH, const char* __restrict__ xL,
    const char* __restrict__ whh, const char* __restrict__ wihb,
    float* __restrict__ PR, float* __restrict__ XPslot) {
  __shared__ __attribute__((aligned(16))) char sm[49152];
  int bx = blockIdx.x;
  if (bx < 512) {
    int n = bx >> 3, s = bx & 7;
    gemm4(hH, hL, whh + (size_t)(n * 32 + s * 4) * 24576, s * 16,
          PR + (size_t)(s * 64 + n) * 24576, sm);
  } else {
    int i = bx - 512, n = i >> 2, s = i & 3;
    gemm4(xH, xL, wihb + (size_t)(n * 16 + s * 4) * 24576, s * 16,
          XPslot + (size_t)(s * 64 + n) * 24576, sm);
  }
}

// Prologue: grp0 = fwd cell xpart (W_ih_f on Xr[0]) -> FP; grp1/2 = xpart(0/1).
__global__ __launch_bounds__(512, 4) void pre_gemm(
    const char* __restrict__ x0H, const char* __restrict__ x0L,
    const char* __restrict__ x1H, const char* __restrict__ x1L,
    const char* __restrict__ wihf, const char* __restrict__ wihb,
    float* __restrict__ FP, float* __restrict__ XP0, float* __restrict__ XP1) {
  __shared__ __attribute__((aligned(16))) char sm[49152];
  int bx = blockIdx.x;
  int grp = bx >> 8, i = bx & 255, n = i >> 2, s = i & 3;
  const char *aH, *aL, *wp; float* dst;
  if (grp == 0)      { aH = x0H; aL = x0L; wp = wihf; dst = FP;  }
  else if (grp == 1) { aH = x0H; aL = x0L; wp = wihb; dst = XP0; }
  else               { aH = x1H; aL = x1L; wp = wihb; dst = XP1; }
  gemm4(aH, aL, wp + (size_t)(n * 16 + s * 4) * 24576, s * 16,
        dst + (size_t)(s * 64 + n) * 24576, sm);
}

// ---------------------------------------------------------------------------
// Reduce slices + bias, apply h = sig(o)*tanh(sig(i)*tanh(g)); write h as
// bf16 hi/lo A-fragments (via LDS transpose) and/or f32 rows of d_out.
// Grid 512 = 64 nstrips x 8 b-octants; 256 thr = 32 j x 8 b-sub.
// ---------------------------------------------------------------------------
__device__ __forceinline__ float sig_(float x) {
  x = fminf(fmaxf(x, -30.f), 30.f);
  return 1.f / (1.f + __expf(-x));
}
__device__ __forceinline__ float tanh_(float x) {
  x = fminf(fmaxf(x, -15.f), 15.f);
  float e = __expf(2.f * x);
  return (e - 1.f) / (e + 1.f);
}

__global__ __launch_bounds__(256) void act_k(
    const float* __restrict__ PR, int nrs,
    const float* __restrict__ XPs, int nxs,
    const float* __restrict__ bias3,
    char* __restrict__ hH, char* __restrict__ hL,
    float* __restrict__ out, int outcol) {
  __shared__ float lds[32][33];
  const int n = blockIdx.x & 63, bo = blockIdx.x >> 6;
  const int tid = threadIdx.x;
  const int j = tid & 31, bs = tid >> 5;
  float ai[4], ag[4], ao[4];
  {
    float b0 = bias3[n * 32 + j];
    float b1 = bias3[2048 + n * 32 + j];
    float b2 = bias3[4096 + n * 32 + j];
#pragma unroll
    for (int r = 0; r < 4; ++r) { ai[r] = b0; ag[r] = b1; ao[r] = b2; }
  }
  for (int s = 0; s < nrs; ++s) {
    const float* p = PR + (size_t)(s * 64 + n) * 24576;
#pragma unroll
    for (int r = 0; r < 4; ++r) {
      int b = bo * 32 + r * 8 + bs;
      ai[r] += p[b * 96 + j];
      ag[r] += p[b * 96 + 32 + j];
      ao[r] += p[b * 96 + 64 + j];
    }
  }
  for (int s = 0; s < nxs; ++s) {
    const float* p = XPs + (size_t)(s * 64 + n) * 24576;
#pragma unroll
    for (int r = 0; r < 4; ++r) {
      int b = bo * 32 + r * 8 + bs;
      ai[r] += p[b * 96 + j];
      ag[r] += p[b * 96 + 32 + j];
      ao[r] += p[b * 96 + 64 + j];
    }
  }
  float hv[4];
#pragma unroll
  for (int r = 0; r < 4; ++r)
    hv[r] = sig_(ao[r]) * tanh_(sig_(ai[r]) * tanh_(ag[r]));

  if (out) {
#pragma unroll
    for (int r = 0; r < 4; ++r)
      out[(size_t)(bo * 32 + r * 8 + bs) * 4096 + outcol + n * 32 + j] = hv[r];
  }
  if (hH) {
#pragma unroll
    for (int r = 0; r < 4; ++r) lds[r * 8 + bs][j] = hv[r];
    __syncthreads();
    const int hl = tid >> 7, lx = tid & 127, joct = lx >> 5, bl = lx & 31;
    bf16x8 w;
#pragma unroll
    for (int e = 0; e < 8; ++e) {
      float v = lds[bl][joct * 8 + e];
      bf16 hb = (bf16)v;
      w[e] = hl ? (bf16)(v - (float)hb) : hb;
    }
    const int jg = n * 32 + joct * 8, bg = bo * 32 + bl;
    size_t off = (size_t)((jg >> 4) * 8 + (bg >> 5)) * 1024
               + (size_t)((bg & 31) + ((jg >> 3) & 1) * 32) * 16;
    *(bf16x8*)((hl ? hL : hH) + off) = w;
  }
}

// ---------------------------------------------------------------------------
extern "C" void kernel_launch(void* const* d_in, const int* in_sizes, int n_in,
                              void* d_out, int out_size, void* d_ws, size_t ws_size,
                              hipStream_t stream) {
  const int*   inputs = (const int*)d_in[0];
  const float* embed  = (const float*)d_in[1];
  const float* Wihf   = (const float*)d_in[2];
  // d_in[3] = W_hh_f: unused (multiplied by zero state in reference)
  const float* bihf   = (const float*)d_in[4];
  const float* bhhf   = (const float*)d_in[5];
  const float* Wihb   = (const float*)d_in[6];
  const float* Whhb   = (const float*)d_in[7];
  const float* bihb   = (const float*)d_in[8];
  const float* bhhb   = (const float*)d_in[9];
  float* out = (float*)d_out;
  char*  ws  = (char*)d_ws;

  size_t o = 0;
  char*  WHHp  = ws + o; o += 50331648;           // 64 jstrips x 32 chunks x 24KB
  char*  WIHBp = ws + o; o += 25165824;           // 64 x 16 x 24KB
  char*  XRH   = ws + o; o += 67108864;           // 128 t x 512KB
  char*  XRL   = ws + o; o += 67108864;
  float* XP    = (float*)(ws + o); o += 75497472; // 3 slots x 4 slices x 6.29MB
  float* PR    = (float*)(ws + o); o += 50331648; // 8 slices x 6.29MB
  char*  WIHFp = (char*)PR;                       // alias: used only in prologue
  char*  HB    = ws + o; o += 4194304;            // h frags: hi0, lo0, hi1, lo1
  float* B3B   = (float*)(ws + o); o += 24576;
  float* B3F   = (float*)(ws + o); o += 24576;
  // total ~340 MB

  const size_t XPS = 25165824 / 4;                // floats per XP slot
  float* FP = XP + 2 * XPS;                       // fwd partials alias slot 2
                                                  // (consumed before step 0 overwrites)

  hipMemsetAsync(HB, 0, 4194304, stream);         // h(-1) = 0 (hi & lo frags)

  pack_w<<<12288, 256, 0, stream>>>(Whhb, WHHp, 32);
  pack_w<<<6144, 256, 0, stream>>>(Wihb, WIHBp, 16);
  pack_w<<<6144, 256, 0, stream>>>(Wihf, WIHFp, 16);
  pack_bias<<<48, 256, 0, stream>>>(bihb, bhhb, bihf, bhhf, B3B, B3F);
  gather_k<<<16384, 256, 0, stream>>>(inputs, embed, XRH, XRL);

  // prologue: fwd-cell xpart + xpart(0) + xpart(1)
  pre_gemm<<<768, 512, 0, stream>>>(XRH, XRL, XRH + 524288, XRL + 524288,
                                    WIHFp, WIHBp, FP, XP, XP + XPS);
  // fwd cell: gates = FP + biasF (h=c=0) -> d_out[:, 0:2048]
  act_k<<<512, 256, 0, stream>>>(FP, 0, FP, 4, B3F, nullptr, nullptr, out, 0);

  char* hHi[2] = {HB, HB + 2097152};
  char* hLo[2] = {HB + 1048576, HB + 3145728};

  for (int t = 0; t < S_; ++t) {
    int tx = (t + 2 > 127) ? 127 : t + 2;         // clamp: harmless recompute
    step_gemm<<<768, 512, 0, stream>>>(
        hHi[t & 1], hLo[t & 1],
        XRH + (size_t)tx * 524288, XRL + (size_t)tx * 524288,
        WHHp, WIHBp, PR, XP + (size_t)((t + 2) % 3) * XPS);
    act_k<<<512, 256, 0, stream>>>(
        PR, 8, XP + (size_t)(t % 3) * XPS, 4, B3B,
        (t < 127) ? hHi[(t & 1) ^ 1] : nullptr,
        (t < 127) ? hLo[(t & 1) ^ 1] : nullptr,
        (t == 127) ? out : nullptr, 2048);
  }
}